// Round 1
// baseline (166.177 us; speedup 1.0000x reference)
//
#include <hip/hip_runtime.h>

#define NB 128
#define NM 60
#define NF 19
#define NA 3
#define NCELL (NF*NF)          // 361
#define NTALL (NB*NA*NCELL)    // 138624
#define NCHTOT 255             // 3 * 85

// anchors / 32
__device__ __constant__ float c_aw[9] = {0.3125f, 0.5f, 1.03125f, 0.9375f, 1.9375f, 1.84375f, 3.625f, 4.875f, 11.65625f};
__device__ __constant__ float c_ah[9] = {0.40625f, 0.9375f, 0.71875f, 1.90625f, 1.40625f, 3.71875f, 2.8125f, 6.1875f, 10.1875f};

__device__ __forceinline__ float clog(float v) { return fmaxf(logf(v), -100.0f); }
__device__ __forceinline__ float sigm(float x) { return 1.0f / (1.0f + expf(-x)); }

__device__ __forceinline__ float wave_sum(float v) {
    for (int off = 32; off > 0; off >>= 1) v += __shfl_down(v, off, 64);
    return v;
}

// Per-(b,m) truth preprocessing
__global__ void k_truth(const float* __restrict__ labels,
                        float* __restrict__ t_tx, float* __restrict__ t_ty,
                        float* __restrict__ t_tw, float* __restrict__ t_th,
                        float* __restrict__ t_scale, float* __restrict__ t_twt,
                        float* __restrict__ t_tht, float* __restrict__ t_txf,
                        float* __restrict__ t_tyf,
                        int* __restrict__ t_valid, int* __restrict__ t_matched,
                        int* __restrict__ t_ti, int* __restrict__ t_tj,
                        int* __restrict__ t_bn, int* __restrict__ t_cls) {
    int idx = blockIdx.x * blockDim.x + threadIdx.x;
    if (idx >= NB * NM) return;
    const float* l = labels + (size_t)idx * 5;
    float x1 = l[0], y1 = l[1], x2 = l[2], y2 = l[3], cf = l[4];
    int valid = ((x1 + y1 + x2 + y2 + cf) > 0.0f) ? 1 : 0;
    float tx = floorf(x1 * (1.0f / 32.0f));
    float ty = floorf(y1 * (1.0f / 32.0f));
    float tw = floorf((x2 - x1) * (1.0f / 32.0f));
    float th = floorf((y2 - y1) * (1.0f / 32.0f));
    int ti = (int)tx, tj = (int)ty;
    // anchor argmax (first-max-wins, like jnp.argmax)
    float best = -1.0f; int bi = 0;
    for (int a = 0; a < 9; a++) {
        float mw = fminf(tw, c_aw[a]), mh = fminf(th, c_ah[a]);
        float inter = (mw > 0.0f && mh > 0.0f) ? mw * mh : 0.0f;
        float iou = inter / (tw * th + c_aw[a] * c_ah[a] - inter);
        if (iou > best) { best = iou; bi = a; }
    }
    int bn = bi % 3;
    t_tx[idx] = tx; t_ty[idx] = ty; t_tw[idx] = tw; t_th[idx] = th;
    t_valid[idx] = valid;
    t_matched[idx] = (valid && bi >= 6) ? 1 : 0;
    t_ti[idx] = ti; t_tj[idx] = tj; t_bn[idx] = bn;
    t_cls[idx] = (int)cf;
    t_twt[idx] = logf(tw / c_aw[6 + bn] + 1e-16f);
    t_tht[idx] = logf(th / c_ah[6 + bn] + 1e-16f);
    t_scale[idx] = sqrtf(2.0f - tw * th * (1.0f / (float)NCELL));
    t_txf[idx] = tx - (float)ti;
    t_tyf[idx] = ty - (float)tj;
}

// Last-write-wins scatter of matched truths into cells (serial m per b, numpy order)
__global__ void k_scatter(const int* __restrict__ t_matched,
                          const int* __restrict__ t_ti, const int* __restrict__ t_tj,
                          const int* __restrict__ t_bn, int* __restrict__ winner) {
    int b = blockIdx.x * blockDim.x + threadIdx.x;
    if (b >= NB) return;
    for (int m = 0; m < NM; m++) {
        int idx = b * NM + m;
        if (t_matched[idx]) {
            int flat = ((b * NA + t_bn[idx]) * NF + t_tj[idx]) * NF + t_ti[idx];
            if (flat >= 0 && flat < NTALL) winner[flat] = m;
        }
    }
}

// Main per-cell loss: one block per (b, anchor), one thread per cell
__launch_bounds__(384)
__global__ void k_main(const float* __restrict__ out,
                       const int* __restrict__ winner,
                       const float* __restrict__ t_tx, const float* __restrict__ t_ty,
                       const float* __restrict__ t_tw, const float* __restrict__ t_th,
                       const int* __restrict__ t_valid,
                       const float* __restrict__ t_scale, const float* __restrict__ t_twt,
                       const float* __restrict__ t_tht, const float* __restrict__ t_txf,
                       const float* __restrict__ t_tyf, const int* __restrict__ t_cls,
                       double* __restrict__ acc) {
    __shared__ float s_x1[NM], s_x2[NM], s_y1[NM], s_y2[NM], s_ar[NM], s_val[NM];
    __shared__ float red[6][5];
    int ba = blockIdx.x;
    int b = ba / NA, a = ba % NA;
    int tid = threadIdx.x;

    if (tid < NM) {
        int idx = b * NM + tid;
        float tx = t_tx[idx], ty = t_ty[idx], tw = t_tw[idx], th = t_th[idx];
        s_x1[tid] = tx - 0.5f * tw; s_x2[tid] = tx + 0.5f * tw;
        s_y1[tid] = ty - 0.5f * th; s_y2[tid] = ty + 0.5f * th;
        s_ar[tid] = tw * th;
        s_val[tid] = t_valid[idx] ? 1.0f : 0.0f;
    }
    __syncthreads();

    bool active = tid < NCELL;
    const float* obase = out + ((size_t)b * NCHTOT + a * 85) * NCELL;
    float r0 = 0.f, r1 = 0.f, r2 = 0.f, r3 = 0.f, r4 = 0.f;
    if (active) {
        r0 = obase[0 * NCELL + tid];
        r1 = obase[1 * NCELL + tid];
        r2 = obase[2 * NCELL + tid];
        r3 = obase[3 * NCELL + tid];
        r4 = obase[4 * NCELL + tid];
    }
    int ii = tid % NF, jj = tid / NF;
    float sx = sigm(r0), sy = sigm(r1), sobj = sigm(r4);
    float pw = expf(r2) * c_aw[6 + a], ph = expf(r3) * c_ah[6 + a];
    float px = sx + (float)ii, py = sy + (float)jj;
    float px1 = px - 0.5f * pw, px2 = px + 0.5f * pw;
    float py1 = py - 0.5f * ph, py2 = py + 0.5f * ph;
    float parea = pw * ph;

    float best = 0.0f;
    for (int m = 0; m < NM; m++) {
        float tlx = fmaxf(px1, s_x1[m]), tly = fmaxf(py1, s_y1[m]);
        float brx = fminf(px2, s_x2[m]), bry = fminf(py2, s_y2[m]);
        if (tlx < brx && tly < bry) {
            float inter = (brx - tlx) * (bry - tly);
            float iou = inter / (parea + s_ar[m] - inter) * s_val[m];
            best = fmaxf(best, iou);
        }
    }

    float lxy = 0.f, lwh = 0.f, lobj = 0.f, lcls = 0.f, ll2 = 0.f;
    if (active) {
        int w = winner[(size_t)ba * NCELL + tid];
        if (w >= 0) {
            int idx = b * NM + w;
            float s = t_scale[idx], s2 = s * s;
            float txf = t_txf[idx], tyf = t_tyf[idx];
            float twt = t_twt[idx], tht = t_tht[idx];
            int k = t_cls[idx];
            lxy = -s2 * (txf * clog(sx) + (1.0f - txf) * clog(1.0f - sx)
                       + tyf * clog(sy) + (1.0f - tyf) * clog(1.0f - sy));
            float dw = r2 - twt, dh = r3 - tht;
            float whsq = s2 * (dw * dw + dh * dh);
            lwh = 0.5f * whsq;
            lobj = -clog(sobj);
            ll2 = (sx - txf) * (sx - txf) + (sy - tyf) * (sy - tyf)
                + whsq + (sobj - 1.0f) * (sobj - 1.0f);
            for (int c = 0; c < 80; c++) {
                float sc = sigm(obase[(5 + c) * NCELL + tid]);
                if (c == k) { lcls -= clog(sc); float d = sc - 1.0f; ll2 += d * d; }
                else        { lcls -= clog(1.0f - sc); ll2 += sc * sc; }
            }
        } else if (best <= 0.5f) {
            lobj = -clog(1.0f - sobj);
            ll2 = sobj * sobj;
        }
    }

    int lane = tid & 63, wid = tid >> 6;
    float v0 = wave_sum(lxy), v1 = wave_sum(lwh), v2 = wave_sum(lobj);
    float v3 = wave_sum(lcls), v4 = wave_sum(ll2);
    if (lane == 0) {
        red[wid][0] = v0; red[wid][1] = v1; red[wid][2] = v2;
        red[wid][3] = v3; red[wid][4] = v4;
    }
    __syncthreads();
    if (tid < 5) {
        float s = 0.0f;
        for (int wv = 0; wv < 6; wv++) s += red[wv][tid];
        atomicAdd(&acc[tid], (double)s);
    }
}

__global__ void k_final(const double* __restrict__ acc, float* __restrict__ o) {
    if (threadIdx.x == 0 && blockIdx.x == 0) {
        double xy = acc[0], wh = acc[1], ob = acc[2], cl = acc[3], l2 = acc[4];
        o[0] = (float)(xy + wh + ob + cl);
        o[1] = (float)xy;
        o[2] = (float)wh;
        o[3] = (float)ob;
        o[4] = (float)cl;
        o[5] = (float)l2;
    }
}

extern "C" void kernel_launch(void* const* d_in, const int* in_sizes, int n_in,
                              void* d_out, int out_size, void* d_ws, size_t ws_size,
                              hipStream_t stream) {
    (void)in_sizes; (void)n_in; (void)out_size; (void)ws_size;
    const float* output = (const float*)d_in[0];
    const float* labels = (const float*)d_in[1];
    float* outp = (float*)d_out;
    char* ws = (char*)d_ws;

    const size_t BM = (size_t)NB * NM;        // 7680
    const size_t A4 = BM * 4;                 // 30720 bytes per array

    double* acc     = (double*)(ws);          // 5 doubles
    char*   base    = ws + 64;
    float* t_tx     = (float*)(base + 0 * A4);
    float* t_ty     = (float*)(base + 1 * A4);
    float* t_tw     = (float*)(base + 2 * A4);
    float* t_th     = (float*)(base + 3 * A4);
    float* t_scale  = (float*)(base + 4 * A4);
    float* t_twt    = (float*)(base + 5 * A4);
    float* t_tht    = (float*)(base + 6 * A4);
    float* t_txf    = (float*)(base + 7 * A4);
    float* t_tyf    = (float*)(base + 8 * A4);
    int*   t_valid  = (int*)  (base + 9 * A4);
    int*   t_matched= (int*)  (base + 10 * A4);
    int*   t_ti     = (int*)  (base + 11 * A4);
    int*   t_tj     = (int*)  (base + 12 * A4);
    int*   t_bn     = (int*)  (base + 13 * A4);
    int*   t_cls    = (int*)  (base + 14 * A4);
    int*   winner   = (int*)  (base + 15 * A4);   // NTALL ints

    hipMemsetAsync(acc, 0, 5 * sizeof(double), stream);
    hipMemsetAsync(winner, 0xFF, (size_t)NTALL * sizeof(int), stream);

    k_truth<<<(NB * NM + 255) / 256, 256, 0, stream>>>(
        labels, t_tx, t_ty, t_tw, t_th, t_scale, t_twt, t_tht, t_txf, t_tyf,
        t_valid, t_matched, t_ti, t_tj, t_bn, t_cls);

    k_scatter<<<2, 64, 0, stream>>>(t_matched, t_ti, t_tj, t_bn, winner);

    k_main<<<NB * NA, 384, 0, stream>>>(
        output, winner, t_tx, t_ty, t_tw, t_th, t_valid,
        t_scale, t_twt, t_tht, t_txf, t_tyf, t_cls, acc);

    k_final<<<1, 64, 0, stream>>>(acc, outp);
}

// Round 2
// 113.759 us; speedup vs baseline: 1.4608x; 1.4608x over previous
//
#include <hip/hip_runtime.h>

#define NB 128
#define NM 60
#define NF 19
#define NA 3
#define NCELL (NF*NF)          // 361
#define NCH 85
#define NCHTOT (NA*NCH)        // 255
#define TPB 192                // threads per block; 2 blocks cover one (b,a) slice
#define NWAVE (TPB/64)         // 3

// anchors / 32
__device__ __constant__ float c_aw[9] = {0.3125f, 0.5f, 1.03125f, 0.9375f, 1.9375f, 1.84375f, 3.625f, 4.875f, 11.65625f};
__device__ __constant__ float c_ah[9] = {0.40625f, 0.9375f, 0.71875f, 1.90625f, 1.40625f, 3.71875f, 2.8125f, 6.1875f, 10.1875f};

__device__ __forceinline__ float clog(float v) { return fmaxf(__logf(v), -100.0f); }
__device__ __forceinline__ float sigm(float x) { return 1.0f / (1.0f + __expf(-x)); }

__device__ __forceinline__ float wave_sum(float v) {
    for (int off = 32; off > 0; off >>= 1) v += __shfl_down(v, off, 64);
    return v;
}

// One fused kernel: truth prep + winner scatter + per-cell losses + cooperative
// class-channel loop + block reduction + atomic accumulate into d_out.
__global__ __launch_bounds__(TPB) void k_main(const float* __restrict__ out,
                                              const float* __restrict__ labels,
                                              float* __restrict__ res) {
    __shared__ float4 s_box[NM];                 // truth x1,y1,x2,y2 (grid units)
    __shared__ float  s_ar[NM];                  // tw*th
    __shared__ float  s_scale[NM], s_twt[NM], s_tht[NM], s_txf[NM], s_tyf[NM];
    __shared__ int    s_cls[NM];
    __shared__ int    s_win[NCELL];              // winner m per cell (-1 = none)
    __shared__ int    s_list[64];                // matched cells: cell | (k<<16)
    __shared__ int    s_n;
    __shared__ float  s_red[NWAVE][5];

    const int blk  = blockIdx.x;
    const int ba   = blk >> 1;                   // (b, a) slice
    const int half = blk & 1;                    // which half of the 361 cells
    const int b = ba / NA, a = ba % NA;
    const int tid = threadIdx.x;
    const int cell = half * TPB + tid;
    const bool active = cell < NCELL;

    // Issue the 5 coalesced channel loads early (no LDS dependence).
    const float* obase = out + ((size_t)b * NCHTOT + a * NCH) * NCELL;
    float r0 = 0.f, r1 = 0.f, r2 = 0.f, r3 = 0.f, r4 = 0.f;
    if (active) {
        r0 = obase[0 * NCELL + cell];
        r1 = obase[1 * NCELL + cell];
        r2 = obase[2 * NCELL + cell];
        r3 = obase[3 * NCELL + cell];
        r4 = obase[4 * NCELL + cell];
    }

    // init winner array + list counter
    for (int c = tid; c < NCELL; c += TPB) s_win[c] = -1;
    if (tid == 0) s_n = 0;
    __syncthreads();

    // ---- truth preprocessing (threads 0..59) ----
    if (tid < NM) {
        const float* l = labels + ((size_t)b * NM + tid) * 5;
        float x1 = l[0], y1 = l[1], x2 = l[2], y2 = l[3], cf = l[4];
        bool valid = (x1 + y1 + x2 + y2 + cf) > 0.0f;
        float tx = floorf(x1 * 0.03125f);
        float ty = floorf(y1 * 0.03125f);
        float tw = floorf((x2 - x1) * 0.03125f);
        float th = floorf((y2 - y1) * 0.03125f);
        int ti = (int)tx, tj = (int)ty;
        // anchor argmax over 9 ref anchors (first-max-wins)
        float bst = -1.0f; int bi = 0;
        #pragma unroll
        for (int q = 0; q < 9; q++) {
            float mw = fminf(tw, c_aw[q]), mh = fminf(th, c_ah[q]);
            float inter = (mw > 0.0f && mh > 0.0f) ? mw * mh : 0.0f;
            float iou = inter / (tw * th + c_aw[q] * c_ah[q] - inter);
            if (iou > bst) { bst = iou; bi = q; }
        }
        int bn = bi % 3;
        // degenerate box for invalid truths -> IoU contributes exactly 0
        s_box[tid] = valid ? make_float4(tx - 0.5f * tw, ty - 0.5f * th,
                                         tx + 0.5f * tw, ty + 0.5f * th)
                           : make_float4(3.0e8f, 3.0e8f, 3.0e8f, 3.0e8f);
        s_ar[tid]    = tw * th;
        s_scale[tid] = sqrtf(2.0f - tw * th * (1.0f / (float)NCELL));
        s_twt[tid]   = __logf(tw / c_aw[6 + bn] + 1e-16f);
        s_tht[tid]   = __logf(th / c_ah[6 + bn] + 1e-16f);
        s_txf[tid]   = tx - (float)ti;
        s_tyf[tid]   = ty - (float)tj;
        s_cls[tid]   = (int)cf;
        // scatter: last-write-wins == max m (verified bit-exact in round 1)
        if (valid && bi >= 6 && bn == a &&
            ti >= 0 && ti < NF && tj >= 0 && tj < NF) {
            atomicMax(&s_win[tj * NF + ti], tid);
        }
    }
    __syncthreads();

    // ---- per-cell decode + best-IoU over 60 truths ----
    int ii = cell % NF, jj = cell / NF;
    float sx = sigm(r0), sy = sigm(r1), sobj = sigm(r4);
    float pw = __expf(r2) * c_aw[6 + a], ph = __expf(r3) * c_ah[6 + a];
    float px = sx + (float)ii, py = sy + (float)jj;
    float px1 = px - 0.5f * pw, px2 = px + 0.5f * pw;
    float py1 = py - 0.5f * ph, py2 = py + 0.5f * ph;
    float parea = pw * ph;

    float best = 0.0f;
    #pragma unroll 4
    for (int m = 0; m < NM; m++) {
        float4 tb = s_box[m];
        float tlx = fmaxf(px1, tb.x), tly = fmaxf(py1, tb.y);
        float brx = fminf(px2, tb.z), bry = fminf(py2, tb.w);
        if (tlx < brx && tly < bry) {
            float inter = (brx - tlx) * (bry - tly);
            best = fmaxf(best, inter / (parea + s_ar[m] - inter));
        }
    }

    // ---- per-cell losses (excluding the 80-class term) ----
    float lxy = 0.f, lwh = 0.f, lobj = 0.f, lcls = 0.f, ll2 = 0.f;
    int w = active ? s_win[cell] : -1;
    if (w >= 0) {
        float s = s_scale[w], s2 = s * s;
        float txf = s_txf[w], tyf = s_tyf[w];
        float dw = r2 - s_twt[w], dh = r3 - s_tht[w];
        lxy = -s2 * (txf * clog(sx) + (1.0f - txf) * clog(1.0f - sx)
                   + tyf * clog(sy) + (1.0f - tyf) * clog(1.0f - sy));
        float whsq = s2 * (dw * dw + dh * dh);
        lwh = 0.5f * whsq;
        lobj = -clog(sobj);
        ll2 = (sx - txf) * (sx - txf) + (sy - tyf) * (sy - tyf)
            + whsq + (sobj - 1.0f) * (sobj - 1.0f);
        int pos = atomicAdd(&s_n, 1);
        s_list[pos] = cell | (s_cls[w] << 16);
    } else if (active && best <= 0.5f) {
        lobj = -clog(1.0f - sobj);
        ll2 = sobj * sobj;
    }
    __syncthreads();

    // ---- cooperative class-channel loop: wave per entry, lane per channel ----
    int nlist = s_n;
    int lane = tid & 63, wid = tid >> 6;
    for (int e = wid; e < nlist; e += NWAVE) {
        int packed = s_list[e];
        int mc = packed & 0xFFFF, k = packed >> 16;
        const float* p = obase + (size_t)5 * NCELL + mc;
        {
            float sc = sigm(p[(size_t)lane * NCELL]);
            bool isk = (lane == k);
            lcls -= isk ? clog(sc) : clog(1.0f - sc);
            float d = isk ? (sc - 1.0f) : sc;
            ll2 += d * d;
        }
        if (lane < 16) {
            int c2 = lane + 64;
            float sc = sigm(p[(size_t)c2 * NCELL]);
            bool isk = (c2 == k);
            lcls -= isk ? clog(sc) : clog(1.0f - sc);
            float d = isk ? (sc - 1.0f) : sc;
            ll2 += d * d;
        }
    }

    // ---- reduction: wave shuffle -> LDS -> atomics into d_out ----
    float v0 = wave_sum(lxy), v1 = wave_sum(lwh), v2 = wave_sum(lobj);
    float v3 = wave_sum(lcls), v4 = wave_sum(ll2);
    if (lane == 0) {
        s_red[wid][0] = v0; s_red[wid][1] = v1; s_red[wid][2] = v2;
        s_red[wid][3] = v3; s_red[wid][4] = v4;
    }
    __syncthreads();
    if (tid < 5) {
        float s = 0.0f;
        for (int wv = 0; wv < NWAVE; wv++) s += s_red[wv][tid];
        atomicAdd(&res[tid + 1], s);          // res[1..5] = xy, wh, obj, cls, l2
        if (tid < 4) atomicAdd(&res[0], s);   // res[0] = xy+wh+obj+cls
    }
}

extern "C" void kernel_launch(void* const* d_in, const int* in_sizes, int n_in,
                              void* d_out, int out_size, void* d_ws, size_t ws_size,
                              hipStream_t stream) {
    (void)in_sizes; (void)n_in; (void)out_size; (void)d_ws; (void)ws_size;
    const float* output = (const float*)d_in[0];
    const float* labels = (const float*)d_in[1];
    float* res = (float*)d_out;

    hipMemsetAsync(res, 0, 6 * sizeof(float), stream);
    k_main<<<NB * NA * 2, TPB, 0, stream>>>(output, labels, res);
}

// Round 3
// 96.962 us; speedup vs baseline: 1.7138x; 1.1732x over previous
//
#include <hip/hip_runtime.h>

#define NB 128
#define NM 60
#define NF 19
#define NA 3
#define NCELL (NF*NF)          // 361
#define NCH 85
#define NCHTOT (NA*NCH)        // 255
#define HALFC 192              // cells per block (half of a (b,a) slice)
#define TPB 384                // 2 groups x 192: grp0 = truths 0..29, grp1 = 30..59
#define NWAVE (TPB/64)         // 6
#define NBLK (NB*NA*2)         // 768

// anchors / 32
__device__ __constant__ float c_aw[9] = {0.3125f, 0.5f, 1.03125f, 0.9375f, 1.9375f, 1.84375f, 3.625f, 4.875f, 11.65625f};
__device__ __constant__ float c_ah[9] = {0.40625f, 0.9375f, 0.71875f, 1.90625f, 1.40625f, 3.71875f, 2.8125f, 6.1875f, 10.1875f};

__device__ __forceinline__ float clog(float v) { return fmaxf(__logf(v), -100.0f); }
__device__ __forceinline__ float sigm(float x) { return 1.0f / (1.0f + __expf(-x)); }

__device__ __forceinline__ float wave_sum(float v) {
    for (int off = 32; off > 0; off >>= 1) v += __shfl_down(v, off, 64);
    return v;
}

// Fused: truth prep + winner scatter + per-cell losses (IoU split across 2
// thread-groups for TLP) + wave-cooperative class loop + store-based partials.
__global__ __launch_bounds__(TPB) void k_main(const float* __restrict__ out,
                                              const float* __restrict__ labels,
                                              float* __restrict__ partial) {
    __shared__ float4 s_box[NM];                 // truth x1,y1,x2,y2 (grid units)
    __shared__ float  s_ar[NM];                  // tw*th
    __shared__ float  s_scale[NM], s_twt[NM], s_tht[NM], s_txf[NM], s_tyf[NM];
    __shared__ int    s_cls[NM];
    __shared__ int    s_win[NCELL];              // winner m per cell (-1 = none)
    __shared__ float  s_hi[HALFC];               // grp1's partial best-IoU
    __shared__ int    s_list[64];                // matched cells: cell | (k<<16)
    __shared__ int    s_n;
    __shared__ float  s_red[NWAVE][5];

    const int blk  = blockIdx.x;
    const int ba   = blk >> 1;                   // (b, a) slice
    const int half = blk & 1;
    const int b = ba / NA, a = ba % NA;
    const int tid = threadIdx.x;
    const int grp   = (tid >= HALFC) ? 1 : 0;
    const int local = tid - grp * HALFC;
    const int cell  = half * HALFC + local;
    const bool active = cell < NCELL;

    // Early coalesced channel loads (grp1 only needs ch0..3 for the pred box).
    const float* obase = out + ((size_t)b * NCHTOT + a * NCH) * NCELL;
    float r0 = 0.f, r1 = 0.f, r2 = 0.f, r3 = 0.f, r4 = 0.f;
    if (active) {
        r0 = obase[0 * NCELL + cell];
        r1 = obase[1 * NCELL + cell];
        r2 = obase[2 * NCELL + cell];
        r3 = obase[3 * NCELL + cell];
        if (grp == 0) r4 = obase[4 * NCELL + cell];
    }

    for (int c = tid; c < NCELL; c += TPB) s_win[c] = -1;
    if (tid == 0) s_n = 0;

    // ---- truth preprocessing (threads 0..59) ----
    if (tid < NM) {
        const float* l = labels + ((size_t)b * NM + tid) * 5;
        float x1 = l[0], y1 = l[1], x2 = l[2], y2 = l[3], cf = l[4];
        bool valid = (x1 + y1 + x2 + y2 + cf) > 0.0f;
        float tx = floorf(x1 * 0.03125f);
        float ty = floorf(y1 * 0.03125f);
        float tw = floorf((x2 - x1) * 0.03125f);
        float th = floorf((y2 - y1) * 0.03125f);
        int ti = (int)tx, tj = (int)ty;
        float bst = -1.0f; int bi = 0;
        #pragma unroll
        for (int q = 0; q < 9; q++) {
            float mw = fminf(tw, c_aw[q]), mh = fminf(th, c_ah[q]);
            float inter = (mw > 0.0f && mh > 0.0f) ? mw * mh : 0.0f;
            float iou = inter / (tw * th + c_aw[q] * c_ah[q] - inter);
            if (iou > bst) { bst = iou; bi = q; }
        }
        int bn = bi % 3;
        // degenerate far-away box for invalid truths -> zero intersection
        s_box[tid] = valid ? make_float4(tx - 0.5f * tw, ty - 0.5f * th,
                                         tx + 0.5f * tw, ty + 0.5f * th)
                           : make_float4(3.0e8f, 3.0e8f, 3.0e8f, 3.0e8f);
        s_ar[tid]    = tw * th;
        s_scale[tid] = sqrtf(2.0f - tw * th * (1.0f / (float)NCELL));
        s_twt[tid]   = __logf(tw / c_aw[6 + bn] + 1e-16f);
        s_tht[tid]   = __logf(th / c_ah[6 + bn] + 1e-16f);
        s_txf[tid]   = tx - (float)ti;
        s_tyf[tid]   = ty - (float)tj;
        s_cls[tid]   = (int)cf;
        // last-write-wins == max m (bit-exact vs reference in rounds 1-2)
        if (valid && bi >= 6 && bn == a &&
            ti >= 0 && ti < NF && tj >= 0 && tj < NF) {
            atomicMax(&s_win[tj * NF + ti], tid);
        }
    }
    __syncthreads();

    // ---- per-cell pred box + best-IoU over this group's 30 truths ----
    int ii = cell % NF, jj = cell / NF;
    float sx = sigm(r0), sy = sigm(r1), sobj = sigm(r4);
    float pw = __expf(r2) * c_aw[6 + a], ph = __expf(r3) * c_ah[6 + a];
    float px = sx + (float)ii, py = sy + (float)jj;
    float px1 = px - 0.5f * pw, px2 = px + 0.5f * pw;
    float py1 = py - 0.5f * ph, py2 = py + 0.5f * ph;
    float parea = pw * ph;

    float best = 0.0f;
    const int mstart = grp * (NM / 2);
    #pragma unroll 5
    for (int m = mstart; m < mstart + NM / 2; m++) {
        float4 tb = s_box[m];
        float dx = fminf(px2, tb.z) - fmaxf(px1, tb.x);
        float dy = fminf(py2, tb.w) - fmaxf(py1, tb.y);
        float inter = fmaxf(dx, 0.0f) * fmaxf(dy, 0.0f);
        best = fmaxf(best, inter * __frcp_rn(parea + s_ar[m] - inter));
    }
    if (grp == 1) s_hi[local] = best;
    __syncthreads();

    // ---- per-cell losses (grp0 only; class term deferred to the list) ----
    float lxy = 0.f, lwh = 0.f, lobj = 0.f, lcls = 0.f, ll2 = 0.f;
    if (grp == 0 && active) {
        best = fmaxf(best, s_hi[local]);
        int w = s_win[cell];
        if (w >= 0) {
            float s = s_scale[w], s2 = s * s;
            float txf = s_txf[w], tyf = s_tyf[w];
            float dw = r2 - s_twt[w], dh = r3 - s_tht[w];
            lxy = -s2 * (txf * clog(sx) + (1.0f - txf) * clog(1.0f - sx)
                       + tyf * clog(sy) + (1.0f - tyf) * clog(1.0f - sy));
            float whsq = s2 * (dw * dw + dh * dh);
            lwh = 0.5f * whsq;
            lobj = -clog(sobj);
            ll2 = (sx - txf) * (sx - txf) + (sy - tyf) * (sy - tyf)
                + whsq + (sobj - 1.0f) * (sobj - 1.0f);
            int pos = atomicAdd(&s_n, 1);
            s_list[pos] = cell | (s_cls[w] << 16);
        } else if (best <= 0.5f) {
            lobj = -clog(1.0f - sobj);
            ll2 = sobj * sobj;
        }
    }
    __syncthreads();

    // ---- cooperative class loop: wave per entry, lane per channel ----
    int nlist = s_n;
    int lane = tid & 63, wid = tid >> 6;
    for (int e = wid; e < nlist; e += NWAVE) {
        int packed = s_list[e];
        int mc = packed & 0xFFFF, k = packed >> 16;
        const float* p = obase + (size_t)5 * NCELL + mc;
        {
            float sc = sigm(p[(size_t)lane * NCELL]);
            bool isk = (lane == k);
            lcls -= isk ? clog(sc) : clog(1.0f - sc);
            float d = isk ? (sc - 1.0f) : sc;
            ll2 += d * d;
        }
        if (lane < 16) {
            int c2 = lane + 64;
            float sc = sigm(p[(size_t)c2 * NCELL]);
            bool isk = (c2 == k);
            lcls -= isk ? clog(sc) : clog(1.0f - sc);
            float d = isk ? (sc - 1.0f) : sc;
            ll2 += d * d;
        }
    }

    // ---- block reduce -> contention-free partial store ----
    float v0 = wave_sum(lxy), v1 = wave_sum(lwh), v2 = wave_sum(lobj);
    float v3 = wave_sum(lcls), v4 = wave_sum(ll2);
    if (lane == 0) {
        s_red[wid][0] = v0; s_red[wid][1] = v1; s_red[wid][2] = v2;
        s_red[wid][3] = v3; s_red[wid][4] = v4;
    }
    __syncthreads();
    if (tid < 5) {
        float s = 0.0f;
        #pragma unroll
        for (int wv = 0; wv < NWAVE; wv++) s += s_red[wv][tid];
        partial[(size_t)blk * 5 + tid] = s;
    }
}

__global__ __launch_bounds__(256) void k_reduce(const float* __restrict__ partial,
                                                float* __restrict__ res) {
    __shared__ float s[4][5];
    int tid = threadIdx.x;
    float acc[5] = {0.f, 0.f, 0.f, 0.f, 0.f};
    for (int i = tid; i < NBLK; i += 256) {
        const float* p = partial + (size_t)i * 5;
        acc[0] += p[0]; acc[1] += p[1]; acc[2] += p[2];
        acc[3] += p[3]; acc[4] += p[4];
    }
    #pragma unroll
    for (int j = 0; j < 5; j++) acc[j] = wave_sum(acc[j]);
    int lane = tid & 63, wid = tid >> 6;
    if (lane == 0) {
        #pragma unroll
        for (int j = 0; j < 5; j++) s[wid][j] = acc[j];
    }
    __syncthreads();
    if (tid == 0) {
        float t[5];
        #pragma unroll
        for (int j = 0; j < 5; j++) t[j] = s[0][j] + s[1][j] + s[2][j] + s[3][j];
        res[0] = t[0] + t[1] + t[2] + t[3];
        res[1] = t[0]; res[2] = t[1]; res[3] = t[2];
        res[4] = t[3]; res[5] = t[4];
    }
}

extern "C" void kernel_launch(void* const* d_in, const int* in_sizes, int n_in,
                              void* d_out, int out_size, void* d_ws, size_t ws_size,
                              hipStream_t stream) {
    (void)in_sizes; (void)n_in; (void)out_size; (void)ws_size;
    const float* output = (const float*)d_in[0];
    const float* labels = (const float*)d_in[1];
    float* res = (float*)d_out;
    float* partial = (float*)d_ws;               // NBLK*5 floats

    k_main<<<NBLK, TPB, 0, stream>>>(output, labels, partial);
    k_reduce<<<1, 256, 0, stream>>>(partial, res);
}